// Round 3
// baseline (1278.591 us; speedup 1.0000x reference)
//
#include <hip/hip_runtime.h>

// 3D neighborhood attention, window 3x3x3, over [B=2, 64,64,64, C=96], NH=6, HD=16.
// Inputs (float32): q [B,H,W,T,C], k [B,H,W,T,C], rpb [6,3,3,3].
// Output (float32): [B, 18, H, W, T]  (channel = head*3 + axis, axis in {di,dj,dl}).

__global__ __launch_bounds__(384) void natt3d_kernel(
    const float* __restrict__ q, const float* __restrict__ k,
    const float* __restrict__ rpb, float* __restrict__ out)
{
    const int blk = blockIdx.x;          // b*4096 + h*64 + w
    const int b = blk >> 12;
    const int h = (blk >> 6) & 63;
    const int w = blk & 63;
    const int tid = (int)threadIdx.x;
    const int n = tid >> 6;              // head 0..5 (wave-uniform)
    const int t = tid & 63;              // consecutive t within a wave

    // ---- load q fragment (16 f32 = 64 B) with scale 0.25
    const float* qp = q + (((size_t)blk << 6) + (size_t)t) * 96 + n * 16;
    float qf[16];
#pragma unroll
    for (int v = 0; v < 4; ++v) {
        const float4 qv = *(const float4*)(qp + 4 * v);
        qf[4 * v + 0] = qv.x * 0.25f;    // SCALE = HD^-0.5 = 0.25
        qf[4 * v + 1] = qv.y * 0.25f;
        qf[4 * v + 2] = qv.z * 0.25f;
        qf[4 * v + 3] = qv.w * 0.25f;
    }

    // ---- 27 window scores (zero for out-of-bounds neighbors, matching zero-pad)
    float sc[27];
    int o = 0;
#pragma unroll
    for (int di = -1; di <= 1; ++di) {
        const int hh = h + di;
        const bool vH = ((unsigned)hh < 64u);
#pragma unroll
        for (int dj = -1; dj <= 1; ++dj) {
            const int ww = w + dj;
            const bool vHW = vH && ((unsigned)ww < 64u);
            const int hc = vHW ? hh : h;   // clamped (wave-uniform) safe address
            const int wc = vHW ? ww : w;
            const float* kcol = k + ((((size_t)b * 64 + hc) * 64 + wc) * 64) * 96 + n * 16;
#pragma unroll
            for (int dl = -1; dl <= 1; ++dl, ++o) {
                const int tt = t + dl;
                const bool valid = vHW && ((unsigned)tt < 64u);
                const int tc = tt < 0 ? 0 : (tt > 63 ? 63 : tt);
                const float* kp = kcol + (size_t)tc * 96;
                float s = 0.f;
#pragma unroll
                for (int v = 0; v < 4; ++v) {
                    const float4 kv = *(const float4*)(kp + 4 * v);
                    s += qf[4 * v + 0] * kv.x;
                    s += qf[4 * v + 1] * kv.y;
                    s += qf[4 * v + 2] * kv.z;
                    s += qf[4 * v + 3] * kv.w;
                }
                sc[o] = valid ? s : 0.f;
            }
        }
    }

    // ---- add relative position bias (rpb[n][i][j][l] flattened matches o order)
#pragma unroll
    for (int oo = 0; oo < 27; ++oo) sc[oo] += rpb[n * 27 + oo];

    // ---- softmax over the 27 window tokens
    float m = sc[0];
#pragma unroll
    for (int oo = 1; oo < 27; ++oo) m = fmaxf(m, sc[oo]);
    float sum = 0.f;
#pragma unroll
    for (int oo = 0; oo < 27; ++oo) { sc[oo] = __expf(sc[oo] - m); sum += sc[oo]; }
    const float inv = 1.0f / sum;

    // ---- contract with fixed offset vectors v[o] = (di, dj, dl)
    float x = 0.f, y = 0.f, z = 0.f;
    o = 0;
#pragma unroll
    for (int di = -1; di <= 1; ++di)
#pragma unroll
        for (int dj = -1; dj <= 1; ++dj)
#pragma unroll
            for (int dl = -1; dl <= 1; ++dl, ++o) {
                const float p = sc[o];
                x += p * (float)di;
                y += p * (float)dj;
                z += p * (float)dl;
            }
    x *= inv; y *= inv; z *= inv;

    // ---- store: out[b][n*3+axis][h][w][t] ; consecutive t => coalesced 4B/lane
    const size_t obase = ((((size_t)b * 18 + (size_t)(n * 3)) * 64 + h) * 64 + w) * 64 + t;
    out[obase]              = x;
    out[obase + 262144]     = y;
    out[obase + 2 * 262144] = z;
}

extern "C" void kernel_launch(void* const* d_in, const int* in_sizes, int n_in,
                              void* d_out, int out_size, void* d_ws, size_t ws_size,
                              hipStream_t stream) {
    const float* q   = (const float*)d_in[0];
    const float* k   = (const float*)d_in[1];
    const float* rpb = (const float*)d_in[2];
    float* out = (float*)d_out;
    (void)in_sizes; (void)n_in; (void)out_size; (void)d_ws; (void)ws_size;

    dim3 grid(2 * 64 * 64);   // one block per (b, h, w) pencil
    dim3 block(384);          // (head, t) = 6 x 64
    natt3d_kernel<<<grid, block, 0, stream>>>(q, k, rpb, out);
}

// Round 4
// 874.937 us; speedup vs baseline: 1.4614x; 1.4614x over previous
//
#include <hip/hip_runtime.h>

// 3D neighborhood attention, window 3x3x3, over [B=2, 64,64,64, C=96], NH=6, HD=16.
// Inputs (float32): q [B,H,W,T,C], k [B,H,W,T,C], rpb [6,3,3,3].
// Output (float32): [B, 18, H, W, T]  (channel = head*3 + axis, axis in {di,dj,dl}).
//
// R4: LDS-staged k. Block = one (b,h,w) pencil, 384 threads = (head n, t).
// Loop over 9 (di,dj) neighbor pencils; cooperatively stage pencil (64t x 96ch
// = 24.6 KB) into LDS with dense coalesced global loads, then conflict-free
// swizzled ds_read_b128 for the 3 dl dot products. Fixes R3's latency-bound
// scattered loads (VALUBusy 6%, HBM 11%, VGPR=36 -> serialized loads).

__global__ __launch_bounds__(384) void natt3d_kernel(
    const float* __restrict__ q, const float* __restrict__ k,
    const float* __restrict__ rpb, float* __restrict__ out)
{
    // [c][t ^ (c&7)] in float4 units: c = 0..23 (16B channel chunk), t = 0..63.
    // Reads (fixed c, lane t): 16B-stride dense permutation -> conflict-free.
    // Writes (c fast across lanes): XOR spreads bank groups.
    __shared__ float4 lds[24 * 64];   // 24576 B -> 5 blocks/CU (wave-slot capped)

    const int blk = blockIdx.x;          // b*4096 + h*64 + w
    const int b = blk >> 12;
    const int h = (blk >> 6) & 63;
    const int w = blk & 63;
    const int tid = (int)threadIdx.x;
    const int n = tid >> 6;              // head 0..5 (wave-uniform)
    const int t = tid & 63;              // lane id = t

    // ---- q fragment (16 f32) with scale 0.25
    const float* qp = q + (((size_t)blk << 6) + (size_t)t) * 96 + n * 16;
    float qf[16];
#pragma unroll
    for (int v = 0; v < 4; ++v) {
        const float4 qv = *(const float4*)(qp + 4 * v);
        qf[4 * v + 0] = qv.x * 0.25f;    // SCALE = HD^-0.5 = 0.25
        qf[4 * v + 1] = qv.y * 0.25f;
        qf[4 * v + 2] = qv.z * 0.25f;
        qf[4 * v + 3] = qv.w * 0.25f;
    }

    // staging map: float4 index g = tid + 384*v over pencil [t][c] (c=0..23)
    const int c0 = tid % 24;             // channel chunk
    const int t0 = tid / 24;             // t-row 0..15; per v add 16
    const int swz = c0 & 7;

    float sc[27];
    int o = 0;
#pragma unroll
    for (int di = -1; di <= 1; ++di) {
        const int hh = h + di;
        const bool vH = ((unsigned)hh < 64u);
#pragma unroll
        for (int dj = -1; dj <= 1; ++dj) {
            const int ww = w + dj;
            const bool vHW = vH && ((unsigned)ww < 64u);
            const int hc = vHW ? hh : h;   // clamped (block-uniform) safe address
            const int wc = vHW ? ww : w;
            const float4* kp = (const float4*)(k + ((((size_t)b * 64 + hc) * 64 + wc) * 64) * 96);

            // issue 4 independent dense loads (overlaps the pre-write barrier)
            float4 kv[4];
#pragma unroll
            for (int v = 0; v < 4; ++v) kv[v] = kp[tid + 384 * v];

            __syncthreads();               // previous iteration's reads done
#pragma unroll
            for (int v = 0; v < 4; ++v)
                lds[c0 * 64 + ((t0 + 16 * v) ^ swz)] = kv[v];
            __syncthreads();               // staging visible

            // 3 dot products (dl = -1,0,+1) from LDS
#pragma unroll
            for (int dl = -1; dl <= 1; ++dl, ++o) {
                const int tt = t + dl;
                const bool valid = vHW && ((unsigned)tt < 64u);
                const int tc = tt < 0 ? 0 : (tt > 63 ? 63 : tt);
                float s = 0.f;
#pragma unroll
                for (int v = 0; v < 4; ++v) {
                    const int c = 4 * n + v;
                    const float4 kx = lds[c * 64 + (tc ^ (c & 7))];
                    s += qf[4 * v + 0] * kx.x;
                    s += qf[4 * v + 1] * kx.y;
                    s += qf[4 * v + 2] * kx.z;
                    s += qf[4 * v + 3] * kx.w;
                }
                sc[o] = valid ? s : 0.f;
            }
        }
    }

    // ---- add relative position bias (rpb[n][i][j][l] matches o order)
#pragma unroll
    for (int oo = 0; oo < 27; ++oo) sc[oo] += rpb[n * 27 + oo];

    // ---- softmax over the 27 window tokens
    float m = sc[0];
#pragma unroll
    for (int oo = 1; oo < 27; ++oo) m = fmaxf(m, sc[oo]);
    float sum = 0.f;
#pragma unroll
    for (int oo = 0; oo < 27; ++oo) { sc[oo] = __expf(sc[oo] - m); sum += sc[oo]; }
    const float inv = 1.0f / sum;

    // ---- contract with fixed offset vectors v[o] = (di, dj, dl)
    float x = 0.f, y = 0.f, z = 0.f;
    o = 0;
#pragma unroll
    for (int di = -1; di <= 1; ++di)
#pragma unroll
        for (int dj = -1; dj <= 1; ++dj)
#pragma unroll
            for (int dl = -1; dl <= 1; ++dl, ++o) {
                const float p = sc[o];
                x += p * (float)di;
                y += p * (float)dj;
                z += p * (float)dl;
            }
    x *= inv; y *= inv; z *= inv;

    // ---- store: out[b][n*3+axis][h][w][t] ; consecutive t => coalesced 4B/lane
    const size_t obase = ((((size_t)b * 18 + (size_t)(n * 3)) * 64 + h) * 64 + w) * 64 + t;
    out[obase]              = x;
    out[obase + 262144]     = y;
    out[obase + 2 * 262144] = z;
}

extern "C" void kernel_launch(void* const* d_in, const int* in_sizes, int n_in,
                              void* d_out, int out_size, void* d_ws, size_t ws_size,
                              hipStream_t stream) {
    const float* q   = (const float*)d_in[0];
    const float* k   = (const float*)d_in[1];
    const float* rpb = (const float*)d_in[2];
    float* out = (float*)d_out;
    (void)in_sizes; (void)n_in; (void)out_size; (void)d_ws; (void)ws_size;

    dim3 grid(2 * 64 * 64);   // one block per (b, h, w) pencil
    dim3 block(384);          // (head, t) = 6 x 64
    natt3d_kernel<<<grid, block, 0, stream>>>(q, k, rpb, out);
}